// Round 1
// baseline (491.784 us; speedup 1.0000x reference)
//
#include <hip/hip_runtime.h>
#include <hip/hip_bf16.h>

#define N_NODES 100000
#define N_EDGES 1600000
#define OUTF 128
#define INF 256
#define SCAN_CHUNK 1024
#define SCAN_BLOCKS 98   // 98*1024 = 100352 >= 100000
#define M_TILES 6250     // 100000 / 16

typedef _Float16 f16;
typedef _Float16 half8 __attribute__((ext_vector_type(8)));
typedef _Float16 half4 __attribute__((ext_vector_type(4)));
typedef _Float16 half2v __attribute__((ext_vector_type(2)));
typedef float floatx4 __attribute__((ext_vector_type(4)));

// ---------------- fused degree count + edge rank (ONE atomic pass) ----------------
__global__ void count_rank_kernel(const int* __restrict__ dst, int E,
                                  int* __restrict__ deg, int* __restrict__ rank) {
    int i = blockIdx.x * blockDim.x + threadIdx.x;
    if (i < E) rank[i] = atomicAdd(&deg[dst[i]], 1);
}

// ---------------- scan step 1: per-chunk sums ----------------
__global__ __launch_bounds__(256) void scan_partial_kernel(const int* __restrict__ deg, int n,
                                                           int* __restrict__ partial) {
    __shared__ int red[256];
    int b = blockIdx.x, t = threadIdx.x;
    int base = b * SCAN_CHUNK;
    int s = 0;
    for (int i = t; i < SCAN_CHUNK; i += 256) {
        int idx = base + i;
        if (idx < n) s += deg[idx];
    }
    red[t] = s;
    __syncthreads();
    for (int off = 128; off > 0; off >>= 1) {
        if (t < off) red[t] += red[t + off];
        __syncthreads();
    }
    if (t == 0) partial[b] = red[0];
}

// ---------------- scan step 2: exclusive scan of partials (nb <= 128) ----------------
__global__ __launch_bounds__(128) void scan_top_kernel(int* __restrict__ partial, int nb,
                                                       int* __restrict__ row_start, int n) {
    __shared__ int sc[128];
    int t = threadIdx.x;
    int v = (t < nb) ? partial[t] : 0;
    sc[t] = v;
    __syncthreads();
    for (int off = 1; off < 128; off <<= 1) {
        int val = sc[t];
        int add = (t >= off) ? sc[t - off] : 0;
        __syncthreads();
        sc[t] = val + add;
        __syncthreads();
    }
    if (t < nb) partial[t] = sc[t] - v;   // exclusive
    if (t == 127) row_start[n] = sc[127]; // total edge count
}

// ---------------- scan step 3: per-chunk exclusive scan + norms ----------------
__global__ __launch_bounds__(256) void scan_final_kernel(const int* __restrict__ deg, int n,
                                                         const int* __restrict__ partial,
                                                         int* __restrict__ row_start,
                                                         float* __restrict__ norm1,
                                                         float* __restrict__ norm2) {
    __shared__ int sc[256];
    int b = blockIdx.x, t = threadIdx.x;
    int base = b * SCAN_CHUNK + t * 4;
    int v[4];
    int tsum = 0;
#pragma unroll
    for (int j = 0; j < 4; j++) {
        int idx = base + j;
        v[j] = (idx < n) ? deg[idx] : 0;
        tsum += v[j];
    }
    sc[t] = tsum;
    __syncthreads();
    for (int off = 1; off < 256; off <<= 1) {
        int val = sc[t];
        int add = (t >= off) ? sc[t - off] : 0;
        __syncthreads();
        sc[t] = val + add;
        __syncthreads();
    }
    int run = sc[t] - tsum + partial[b];
#pragma unroll
    for (int j = 0; j < 4; j++) {
        int idx = base + j;
        if (idx < n) {
            row_start[idx] = run;
            float d = (float)(v[j] > 0 ? v[j] : 1); // clip(deg, 1)
            norm1[idx] = rsqrtf(d);
            norm2[idx] = 1.0f / d;
            run += v[j];
        }
    }
}

// ---------------- edge scatter into CSR slots (atomic-free) ----------------
__global__ void scatter_edges_kernel(const int* __restrict__ src, const int* __restrict__ dst,
                                     const int* __restrict__ rank,
                                     const int* __restrict__ row_start,
                                     int E, int* __restrict__ srcs_sorted) {
    int i = blockIdx.x * blockDim.x + threadIdx.x;
    if (i < E) {
        srcs_sorted[row_start[dst[i]] + rank[i]] = src[i];
    }
}

// ---------------- convert W_mean|W_var into f16 Bt, wave-friendly layout ----------------
// Bt row ng = g*16 + i, g in [0,16): g = ch*8 + w*2 + cg
//   ch = column half (0/1), w = wave (0..3), cg: 0 -> mean, 1 -> var
// actual col = ch*64 + w*16 + i (0..127);  Bt[ng][k] = W[k][col]
__global__ __launch_bounds__(256) void convert_B_kernel(const float* __restrict__ Wm,
                                                        const float* __restrict__ Wv,
                                                        f16* __restrict__ Bt) {
    int k = threadIdx.x;
    int ng = blockIdx.x;
    int g = ng >> 4, i = ng & 15;
    int ch = g >> 3, w = (g >> 1) & 3, cg = g & 1;
    int col = ch * 64 + w * 16 + i;
    const float* srcW = cg ? Wv : Wm;
    Bt[ng * 256 + k] = (f16)srcW[k * 128 + col];
}

// ---------------- MFMA projection + relu + attention + msg (f16) ----------------
// block = 256 (4 waves). Grid = 2500: blockIdx&1 selects column half (64 cols),
// blockIdx>>1 selects tile chunk (1250 chunks x 5 tiles grid-stride).
// Wave w owns cols [ch*64 + w*16, +16) for BOTH mean & var.
// B frags = b[2][8] = 64 VGPRs/lane -> genuinely register-resident (the previous
// version's b[4][8] needed 128 VGPRs and was spilled/rematerialized every tile:
// VGPR_Count=88 proved it; that spill-reload was the 123 us latency wall).
// msg layout: interleaved (m,v) pairs: msg[node*256 + 2*col] = m, +1 = v
//   -> 4 B paired stores here, single 8 B gather per edge per lane in agg.
__global__ __launch_bounds__(256, 3) void proj_mfma_kernel(const float* __restrict__ feat,
                                                           const f16* __restrict__ Bt,
                                                           const float* __restrict__ norm1,
                                                           const float* __restrict__ norm2,
                                                           f16* __restrict__ msg) {
    int tid = threadIdx.x;
    int w = tid >> 6;
    int lane = tid & 63;
    int quad = lane >> 4;
    int l15 = lane & 15;
    int ch = blockIdx.x & 1;
    int tbase = blockIdx.x >> 1;

    // load B fragments once: 2 col-groups (mean/var, same 16 cols) x 8 k-frags
    half8 b[2][8];
#pragma unroll
    for (int cg = 0; cg < 2; cg++) {
        int g = ch * 8 + w * 2 + cg;
        const f16* bp = Bt + (size_t)(g * 16 + l15) * 256 + quad * 8;
#pragma unroll
        for (int kf = 0; kf < 8; kf++) {
            b[cg][kf] = *(const half8*)(bp + kf * 32);
        }
    }

    int col = ch * 64 + w * 16 + l15; // 0..127

    for (int t = tbase; t < M_TILES; t += 1250) {
        int m0 = t * 16;
        half8 a[8];
        const float* ap = feat + (size_t)(m0 + l15) * 256 + quad * 8;
#pragma unroll
        for (int kf = 0; kf < 8; kf++) {
            floatx4 f0 = *(const floatx4*)(ap + kf * 32);
            floatx4 f1 = *(const floatx4*)(ap + kf * 32 + 4);
            half8 h;
            h[0] = (f16)f0.x; h[1] = (f16)f0.y; h[2] = (f16)f0.z; h[3] = (f16)f0.w;
            h[4] = (f16)f1.x; h[5] = (f16)f1.y; h[6] = (f16)f1.z; h[7] = (f16)f1.w;
            a[kf] = h;
        }

        // hoist norm loads so they overlap the MFMA chain
        float s1r[4], s2r[4];
#pragma unroll
        for (int r = 0; r < 4; r++) {
            int node = m0 + quad * 4 + r;
            s1r[r] = norm1[node];
            s2r[r] = norm2[node];
        }

        floatx4 acc0 = (floatx4){0.f, 0.f, 0.f, 0.f};
        floatx4 acc1 = (floatx4){0.f, 0.f, 0.f, 0.f};
#pragma unroll
        for (int kf = 0; kf < 8; kf++) {
            acc0 = __builtin_amdgcn_mfma_f32_16x16x32_f16(a[kf], b[0][kf], acc0, 0, 0, 0);
            acc1 = __builtin_amdgcn_mfma_f32_16x16x32_f16(a[kf], b[1][kf], acc1, 0, 0, 0);
        }

        // epilogue: paired (m,v) 4 B stores
#pragma unroll
        for (int r = 0; r < 4; r++) {
            int node = m0 + quad * 4 + r;
            float m = fmaxf(acc0[r], 0.f);
            float v = fmaxf(acc1[r], 0.f);
            float att = __expf(-v); // GAMMA = 1
            half2v pr;
            pr[0] = (f16)(m * att * s1r[r]);
            pr[1] = (f16)(v * att * att * s2r[r]);
            *(half2v*)(msg + (size_t)node * 256 + col * 2) = pr;
        }
    }
}

// ---------------- per-dst aggregation (wave per dst) + final norm ----------------
// msg row: 128 interleaved (m,v) f16 pairs (512 B). lane covers cols 2*lane, 2*lane+1
// via ONE 8 B load per edge: half4 = {m[2l], v[2l], m[2l+1], v[2l+1]}.
__global__ __launch_bounds__(256) void agg_kernel(const int* __restrict__ row_start,
                                                  const int* __restrict__ srcs,
                                                  const f16* __restrict__ msg,
                                                  const float* __restrict__ norm1,
                                                  const float* __restrict__ norm2,
                                                  float* __restrict__ out_mean,
                                                  float* __restrict__ out_var) {
    int d = blockIdx.x * 4 + (threadIdx.x >> 6);
    int lane = threadIdx.x & 63;
    int s0 = row_start[d];
    int s1 = row_start[d + 1];
    float am0 = 0.f, am1 = 0.f, av0 = 0.f, av1 = 0.f;
    int i = s0;
    for (; i + 7 < s1; i += 8) {
        half4 h[8];
#pragma unroll
        for (int j = 0; j < 8; j++) {
            h[j] = *(const half4*)(msg + (size_t)srcs[i + j] * 256 + lane * 4);
        }
#pragma unroll
        for (int j = 0; j < 8; j++) {
            am0 += (float)h[j][0];
            av0 += (float)h[j][1];
            am1 += (float)h[j][2];
            av1 += (float)h[j][3];
        }
    }
    for (; i < s1; i++) {
        half4 ha = *(const half4*)(msg + (size_t)srcs[i] * 256 + lane * 4);
        am0 += (float)ha[0];
        av0 += (float)ha[1];
        am1 += (float)ha[2];
        av1 += (float)ha[3];
    }
    float k1 = norm1[d], k2 = norm2[d];
    float2 om = make_float2(am0 * k1, am1 * k1);
    float2 ov = make_float2(av0 * k2, av1 * k2);
    *(float2*)(out_mean + (size_t)d * 128 + lane * 2) = om;
    *(float2*)(out_var + (size_t)d * 128 + lane * 2) = ov;
}

extern "C" void kernel_launch(void* const* d_in, const int* in_sizes, int n_in,
                              void* d_out, int out_size, void* d_ws, size_t ws_size,
                              hipStream_t stream) {
    const float* feat = (const float*)d_in[0];
    const float* Wm = (const float*)d_in[1];
    const float* Wv = (const float*)d_in[2];
    const int* src = (const int*)d_in[3];
    const int* dst = (const int*)d_in[4];
    float* out = (float*)d_out;

    const int N = N_NODES;
    const int E = N_EDGES;

    char* wsp = (char*)d_ws;
    auto carve = [&](size_t bytes) {
        char* p = wsp;
        wsp += (bytes + 255) & ~(size_t)255;
        return p;
    };
    f16* msg = (f16*)carve((size_t)N * 256 * sizeof(f16));   // (m,v) pairs, 51.2 MB
    f16* Bt = (f16*)carve((size_t)256 * 256 * sizeof(f16));  // 128 KB
    int* srcs_sorted = (int*)carve((size_t)E * 4);
    int* rank = (int*)carve((size_t)E * 4);
    int* deg = (int*)carve((size_t)N * 4);
    int* row_start = (int*)carve((size_t)(N + 1) * 4);
    float* norm1 = (float*)carve((size_t)N * 4);
    float* norm2 = (float*)carve((size_t)N * 4);
    int* partial = (int*)carve(128 * 4);

    hipMemsetAsync(deg, 0, (size_t)N * 4, stream);

    count_rank_kernel<<<(E + 255) / 256, 256, 0, stream>>>(dst, E, deg, rank);
    convert_B_kernel<<<256, 256, 0, stream>>>(Wm, Wv, Bt);
    scan_partial_kernel<<<SCAN_BLOCKS, 256, 0, stream>>>(deg, N, partial);
    scan_top_kernel<<<1, 128, 0, stream>>>(partial, SCAN_BLOCKS, row_start, N);
    scan_final_kernel<<<SCAN_BLOCKS, 256, 0, stream>>>(deg, N, partial, row_start, norm1, norm2);
    scatter_edges_kernel<<<(E + 255) / 256, 256, 0, stream>>>(src, dst, rank, row_start, E,
                                                              srcs_sorted);
    proj_mfma_kernel<<<2500, 256, 0, stream>>>(feat, Bt, norm1, norm2, msg);
    agg_kernel<<<N / 4, 256, 0, stream>>>(row_start, srcs_sorted, msg, norm1, norm2,
                                          out, out + (size_t)N * OUTF);
}